// Round 2
// baseline (420.715 us; speedup 1.0000x reference)
//
#include <hip/hip_runtime.h>
#include <cstdint>
#include <cstddef>

#define DEV static __device__ __forceinline__

constexpr int TT   = 8192;   // B*S tokens
constexpr int DD   = 1024;   // d_model
constexpr int DFF  = 512;
constexpr int NE   = 16;
constexpr int FDFF = 1024;   // fused shared dff
constexpr int NSLOT = TT * 2;                 // token-expert pairs
constexpr int NSLOT_PAD = NSLOT + NE * 128;   // padded to 128-row tiles
constexpr int MAXT = NSLOT / 128 + NE;        // 144 max live m-tiles
constexpr int HB   = 64;                      // hist blocks (256 entries each)

// ---- workspace layout (bytes) ----
constexpr size_t XB_OFF   = 0;                                    // x bf16 [T,D]
constexpr size_t HS_OFF   = XB_OFF  + (size_t)TT * DD * 2;        // shared hidden bf16 [T,FDFF]
constexpr size_t HR_OFF   = HS_OFF  + (size_t)TT * FDFF * 2;      // routed hidden bf16 [NSLOT_PAD,DFF]
constexpr size_t YR_OFF   = HR_OFF  + (size_t)NSLOT_PAD * DFF * 2;// routed out bf16 [NSLOT_PAD,DD]
constexpr size_t W1B_OFF  = YR_OFF  + (size_t)NSLOT_PAD * DD * 2;
constexpr size_t W3B_OFF  = W1B_OFF + (size_t)NE * DFF * DD * 2;
constexpr size_t W2B_OFF  = W3B_OFF + (size_t)NE * DFF * DD * 2;
constexpr size_t SW1B_OFF = W2B_OFF + (size_t)NE * DD * DFF * 2;
constexpr size_t SW3B_OFF = SW1B_OFF + (size_t)FDFF * DD * 2;
constexpr size_t SW2B_OFF = SW3B_OFF + (size_t)FDFF * DD * 2;
constexpr size_t TKI_OFF  = SW2B_OFF + (size_t)DD * FDFF * 2;
constexpr size_t TKW_OFF  = TKI_OFF + (size_t)NSLOT * 4;
constexpr size_t STOK_OFF = TKW_OFF + (size_t)NSLOT * 4;
constexpr size_t TSL_OFF  = STOK_OFF + (size_t)NSLOT_PAD * 4;     // token-pair -> slot [NSLOT]
constexpr size_t LRK_OFF  = TSL_OFF + (size_t)NSLOT * 4;          // local rank [NSLOT]
constexpr size_t BCN_OFF  = LRK_OFF + (size_t)NSLOT * 4;          // blockCnt [HB][16]
constexpr size_t BB_OFF   = BCN_OFF + (size_t)HB * NE * 4;        // blockBase [HB][16]
constexpr size_t OFS_OFF  = BB_OFF + (size_t)HB * NE * 4;         // offsets[17]
constexpr size_t TEX_OFF  = OFS_OFF + 128;                        // tile->expert
constexpr size_t TM0_OFF  = TEX_OFF + (size_t)MAXT * 4;           // tile->slot0

typedef __bf16 bf16x8 __attribute__((ext_vector_type(8)));
typedef float  floatx4 __attribute__((ext_vector_type(4)));
typedef unsigned short u16t;

DEV unsigned f2bf2(float lo, float hi) {
    unsigned a = __builtin_bit_cast(unsigned, lo);
    unsigned b = __builtin_bit_cast(unsigned, hi);
    a += 0x7FFFu + ((a >> 16) & 1u);
    b += 0x7FFFu + ((b >> 16) & 1u);
    return (a >> 16) | (b & 0xFFFF0000u);
}
DEV u16t f2bf1(float f) {
    unsigned u = __builtin_bit_cast(unsigned, f);
    u += 0x7FFFu + ((u >> 16) & 1u);
    return (u16t)(u >> 16);
}
DEV float bf2f(u16t v) {
    return __builtin_bit_cast(float, ((unsigned)v) << 16);
}
DEV uint4 pack8(float4 a, float4 b) {
    uint4 r;
    r.x = f2bf2(a.x, a.y); r.y = f2bf2(a.z, a.w);
    r.z = f2bf2(b.x, b.y); r.w = f2bf2(b.z, b.w);
    return r;
}
DEV floatx4 mfma16(bf16x8 a, bf16x8 b, floatx4 c) {
    return __builtin_amdgcn_mfma_f32_16x16x32_bf16(a, b, c, 0, 0, 0);
}
DEV void glds16(const u16t* g, u16t* l) {   // async global->LDS, 16B/lane
    __builtin_amdgcn_global_load_lds(
        (const __attribute__((address_space(1))) unsigned int*)g,
        (__attribute__((address_space(3))) unsigned int*)l, 16, 0, 0);
}
DEV float dot4(float4 a, float4 b) { return a.x*b.x + a.y*b.y + a.z*b.z + a.w*b.w; }

// ---------------- weight fp32 -> bf16 pre-convert ----------------
__global__ __launch_bounds__(256) void k_cvtw(
        const float* __restrict__ w1, const float* __restrict__ w3, const float* __restrict__ w2,
        const float* __restrict__ sw1, const float* __restrict__ sw3, const float* __restrict__ sw2,
        u16t* __restrict__ w1b, u16t* __restrict__ w3b, u16t* __restrict__ w2b,
        u16t* __restrict__ sw1b, u16t* __restrict__ sw3b, u16t* __restrict__ sw2b) {
    int b = blockIdx.x;
    const float* src; u16t* dst; size_t base;
    if      (b < 4096)  { src = w1;  dst = w1b;  base = (size_t)b * 2048; }
    else if (b < 8192)  { src = w3;  dst = w3b;  base = (size_t)(b - 4096) * 2048; }
    else if (b < 12288) { src = w2;  dst = w2b;  base = (size_t)(b - 8192) * 2048; }
    else if (b < 12800) { src = sw1; dst = sw1b; base = (size_t)(b - 12288) * 2048; }
    else if (b < 13312) { src = sw3; dst = sw3b; base = (size_t)(b - 12800) * 2048; }
    else                { src = sw2; dst = sw2b; base = (size_t)(b - 13312) * 2048; }
    size_t i = base + (size_t)threadIdx.x * 8;
    float4 a = *(const float4*)(src + i);
    float4 c = *(const float4*)(src + i + 4);
    *(uint4*)(dst + i) = pack8(a, c);
}

// ---------------- gate: top-2 + fused x->bf16 conversion ----------------
__global__ __launch_bounds__(256) void k_gate(const float* __restrict__ x,
                                              const float* __restrict__ gw,
                                              const float* __restrict__ eb,
                                              int* __restrict__ tki, float* __restrict__ tkw,
                                              u16t* __restrict__ xb) {
    const int tid = threadIdx.x;
    const int wave = tid >> 6, lane = tid & 63;
    const int tok0 = blockIdx.x * 16 + wave * 4;
    float acc[4][16];
#pragma unroll
    for (int t = 0; t < 4; t++)
#pragma unroll
        for (int e = 0; e < 16; e++) acc[t][e] = 0.f;
#pragma unroll
    for (int i = 0; i < 4; i++) {
        const int d = i * 256 + lane * 4;
        float4 xv[4];
#pragma unroll
        for (int t = 0; t < 4; t++) xv[t] = *(const float4*)(x + (size_t)(tok0 + t) * DD + d);
        // fused bf16 conversion of x (replaces k_cvtx: saves a full re-read of x)
#pragma unroll
        for (int t = 0; t < 4; t++) {
            uint2 p;
            p.x = f2bf2(xv[t].x, xv[t].y);
            p.y = f2bf2(xv[t].z, xv[t].w);
            *(uint2*)(xb + (size_t)(tok0 + t) * DD + d) = p;
        }
#pragma unroll
        for (int e = 0; e < 16; e++) {
            float4 wv = *(const float4*)(gw + (size_t)e * DD + d);
#pragma unroll
            for (int t = 0; t < 4; t++) acc[t][e] += dot4(xv[t], wv);
        }
    }
#pragma unroll
    for (int t = 0; t < 4; t++)
#pragma unroll
        for (int e = 0; e < 16; e++) {
            float v = acc[t][e];
            v += __shfl_xor(v, 1);  v += __shfl_xor(v, 2);  v += __shfl_xor(v, 4);
            v += __shfl_xor(v, 8);  v += __shfl_xor(v, 16); v += __shfl_xor(v, 32);
            acc[t][e] = v;
        }
    if (lane == 0) {
        float ebs[16];
#pragma unroll
        for (int e = 0; e < 16; e++) ebs[e] = eb[e];
#pragma unroll
        for (int t = 0; t < 4; t++) {
            float b0 = -1e30f, b1v = -1e30f, l0 = 0.f, l1 = 0.f;
            int i0 = 0, i1 = 0;
#pragma unroll
            for (int e = 0; e < 16; e++) {
                float lv = acc[t][e];
                float bl = lv + ebs[e];
                if (bl > b0)       { b1v = b0; i1 = i0; l1 = l0; b0 = bl; i0 = e; l0 = lv; }
                else if (bl > b1v) { b1v = bl; i1 = e; l1 = lv; }
            }
            float s0 = 1.f / (1.f + expf(-l0));
            float s1 = 1.f / (1.f + expf(-l1));
            float dn = s0 + s1 + 1e-10f;
            int tok = tok0 + t;
            tki[tok * 2] = i0; tki[tok * 2 + 1] = i1;
            tkw[tok * 2] = s0 / dn; tkw[tok * 2 + 1] = s1 / dn;
        }
    }
}

// ---------------- hist: per-block LDS histogram + local ranks ----------------
__global__ __launch_bounds__(256) void k_hist(const int* __restrict__ tki,
                                              int* __restrict__ lrank, int* __restrict__ bcnt) {
    __shared__ int h[NE];
    const int tid = threadIdx.x;
    if (tid < NE) h[tid] = 0;
    __syncthreads();
    int idx = blockIdx.x * 256 + tid;
    int e = tki[idx];
    lrank[idx] = atomicAdd(&h[e], 1);   // LDS atomic -- no global contention
    __syncthreads();
    if (tid < NE) bcnt[blockIdx.x * NE + tid] = h[tid];
}

// ---------------- scan: expert offsets (128-padded), tile map, block bases ----------------
__global__ void k_scan(const int* __restrict__ bcnt, int* __restrict__ offs,
                       int* __restrict__ bb, int* __restrict__ texp, int* __restrict__ tm0) {
    __shared__ int cntS[NE], offS[NE];
    const int tid = threadIdx.x;
    if (tid < NE) {
        int s = 0;
#pragma unroll
        for (int b = 0; b < HB; b++) s += bcnt[b * NE + tid];
        cntS[tid] = s;
    }
    __syncthreads();
    if (tid == 0) {
        int off = 0, t = 0;
        for (int e = 0; e < NE; e++) {
            offS[e] = off; offs[e] = off;
            int nt = (cntS[e] + 127) >> 7;
            for (int i = 0; i < nt; i++) { texp[t] = e; tm0[t] = off + i * 128; t++; }
            off += nt * 128;
        }
        offs[NE] = off;
        for (; t < MAXT; t++) texp[t] = -1;
    }
    __syncthreads();
    if (tid < NE) {
        int run = offS[tid];
        for (int b = 0; b < HB; b++) { bb[b * NE + tid] = run; run += bcnt[b * NE + tid]; }
    }
}

// ---------------- scatter: pure gather/store, zero atomics; also inverse map ----------------
__global__ __launch_bounds__(256) void k_scatter(const int* __restrict__ tki,
                                                 const int* __restrict__ bb,
                                                 const int* __restrict__ lrank,
                                                 int* __restrict__ stok,
                                                 int* __restrict__ tslot) {
    int idx = blockIdx.x * 256 + threadIdx.x;
    int e = tki[idx];
    int slot = bb[blockIdx.x * NE + e] + lrank[idx];
    stok[slot] = idx >> 1;
    tslot[idx] = slot;          // inverse map: token-pair -> slot (for fused combine)
}

// ======== 2-phase double-buffered GEMM kernels ========
// Schedule per K-step: STAGE(next buf) issued BEFORE compute(current buf);
// single __syncthreads() per step (its implicit vmcnt(0) drains the prefetch
// after ~16 MFMA of overlap). Unrolled x2 so buffer indices are static.

// ---------------- shared GEMM1 (dual 128x64, dbuf): Hs = swiglu ----------------
__global__ __launch_bounds__(256) void k_sgemm1(const u16t* __restrict__ xb,
        const u16t* __restrict__ w1b, const float* __restrict__ sb1,
        const u16t* __restrict__ w3b, const float* __restrict__ sb3,
        u16t* __restrict__ Hs) {
    __shared__ u16t As[2][128 * 32], B1s[2][64 * 32], B3s[2][64 * 32];
    const int m0 = blockIdx.x * 128, n0 = blockIdx.y * 64;
    const int tid = threadIdx.x, lane = tid & 63, wid = tid >> 6;
    const int wm = (wid & 1) * 64, wn = (wid >> 1) * 32;
    const int q = lane >> 4, r = lane & 15;
    const int srow = tid >> 2, scg = (tid & 3) * 8;
    floatx4 acc1[4][2], acc3[4][2];
#pragma unroll
    for (int i = 0; i < 4; i++)
#pragma unroll
        for (int j = 0; j < 2; j++) { acc1[i][j] = (floatx4)0.f; acc3[i][j] = (floatx4)0.f; }
    const u16t* a0  = xb  + (size_t)(m0 + srow) * DD + scg;
    const u16t* a1  = xb  + (size_t)(m0 + 64 + srow) * DD + scg;
    const u16t* b1g = w1b + (size_t)(n0 + srow) * DD + scg;
    const u16t* b3g = w3b + (size_t)(n0 + srow) * DD + scg;

#define SG1_STAGE(bf, kk) do { \
        glds16(a0 + (kk), &As[bf][tid * 8]); \
        glds16(a1 + (kk), &As[bf][2048 + tid * 8]); \
        glds16(b1g + (kk), &B1s[bf][tid * 8]); \
        glds16(b3g + (kk), &B3s[bf][tid * 8]); \
    } while (0)
#define SG1_COMP(bf) do { \
        bf16x8 af[4], f1[2], f3[2]; \
        _Pragma("unroll") \
        for (int i = 0; i < 4; i++) af[i] = *(const bf16x8*)&As[bf][(wm + i * 16 + r) * 32 + q * 8]; \
        _Pragma("unroll") \
        for (int j = 0; j < 2; j++) { \
            f1[j] = *(const bf16x8*)&B1s[bf][(wn + j * 16 + r) * 32 + q * 8]; \
            f3[j] = *(const bf16x8*)&B3s[bf][(wn + j * 16 + r) * 32 + q * 8]; \
        } \
        _Pragma("unroll") \
        for (int i = 0; i < 4; i++) \
            _Pragma("unroll") \
            for (int j = 0; j < 2; j++) { \
                acc1[i][j] = mfma16(af[i], f1[j], acc1[i][j]); \
                acc3[i][j] = mfma16(af[i], f3[j], acc3[i][j]); \
            } \
    } while (0)

    SG1_STAGE(0, 0);
    __syncthreads();
    for (int k0 = 0; k0 + 64 <= DD; k0 += 64) {
        SG1_STAGE(1, k0 + 32);
        SG1_COMP(0);
        __syncthreads();
        if (k0 + 64 < DD) SG1_STAGE(0, k0 + 64);
        SG1_COMP(1);
        __syncthreads();
    }
#undef SG1_STAGE
#undef SG1_COMP
    float s1v[2], s3v[2];
#pragma unroll
    for (int j = 0; j < 2; j++) {
        int col = n0 + wn + j * 16 + r;
        s1v[j] = sb1[col]; s3v[j] = sb3[col];
    }
#pragma unroll
    for (int i = 0; i < 4; i++)
#pragma unroll
        for (int j = 0; j < 2; j++)
#pragma unroll
            for (int g = 0; g < 4; g++) {
                int row = m0 + wm + i * 16 + q * 4 + g;
                int col = n0 + wn + j * 16 + r;
                float z1 = acc1[i][j][g] + s1v[j];
                float z3 = acc3[i][j][g] + s3v[j];
                float h = (z1 / (1.f + __expf(-z1))) * z3;
                Hs[(size_t)row * FDFF + col] = f2bf1(h);
            }
}

// ---------------- shared GEMM2 + fused routed combine (dbuf) ----------------
// out[t] = Hs[t]@sw2^T + sb2 + tkw[t,0]*Yr[slot0] + tkw[t,1]*Yr[slot1]
__global__ __launch_bounds__(256) void k_sgemm2(const u16t* __restrict__ Hs,
        const u16t* __restrict__ sw2b, const float* __restrict__ sb2,
        const u16t* __restrict__ Yr, const int* __restrict__ tslot,
        const float* __restrict__ tkw,
        float* __restrict__ out) {
    __shared__ u16t As[2][128 * 32], Bs[2][128 * 32];
    __shared__ int sl[256];
    __shared__ float wl[256];
    const int m0 = blockIdx.x * 128, n0 = blockIdx.y * 128;
    const int tid = threadIdx.x, lane = tid & 63, wid = tid >> 6;
    const int wm = (wid & 1) * 64, wn = (wid >> 1) * 64;
    const int q = lane >> 4, r = lane & 15;
    const int srow = tid >> 2, scg = (tid & 3) * 8;
    sl[tid] = tslot[m0 * 2 + tid];
    wl[tid] = tkw[m0 * 2 + tid];
    floatx4 acc[4][4];
#pragma unroll
    for (int i = 0; i < 4; i++)
#pragma unroll
        for (int j = 0; j < 4; j++) acc[i][j] = (floatx4)0.f;
    const u16t* a0 = Hs + (size_t)(m0 + srow) * FDFF + scg;
    const u16t* a1 = Hs + (size_t)(m0 + 64 + srow) * FDFF + scg;
    const u16t* b0 = sw2b + (size_t)(n0 + srow) * FDFF + scg;
    const u16t* b1 = sw2b + (size_t)(n0 + 64 + srow) * FDFF + scg;

#define SG2_STAGE(bf, kk) do { \
        glds16(a0 + (kk), &As[bf][tid * 8]); \
        glds16(a1 + (kk), &As[bf][2048 + tid * 8]); \
        glds16(b0 + (kk), &Bs[bf][tid * 8]); \
        glds16(b1 + (kk), &Bs[bf][2048 + tid * 8]); \
    } while (0)
#define SG2_COMP(bf) do { \
        bf16x8 af[4], bfr[4]; \
        _Pragma("unroll") \
        for (int i = 0; i < 4; i++) af[i] = *(const bf16x8*)&As[bf][(wm + i * 16 + r) * 32 + q * 8]; \
        _Pragma("unroll") \
        for (int j = 0; j < 4; j++) bfr[j] = *(const bf16x8*)&Bs[bf][(wn + j * 16 + r) * 32 + q * 8]; \
        _Pragma("unroll") \
        for (int i = 0; i < 4; i++) \
            _Pragma("unroll") \
            for (int j = 0; j < 4; j++) acc[i][j] = mfma16(af[i], bfr[j], acc[i][j]); \
    } while (0)

    SG2_STAGE(0, 0);
    __syncthreads();
    for (int k0 = 0; k0 + 64 <= FDFF; k0 += 64) {
        SG2_STAGE(1, k0 + 32);
        SG2_COMP(0);
        __syncthreads();
        if (k0 + 64 < FDFF) SG2_STAGE(0, k0 + 64);
        SG2_COMP(1);
        __syncthreads();
    }
#undef SG2_STAGE
#undef SG2_COMP
    float bv[4];
#pragma unroll
    for (int j = 0; j < 4; j++) bv[j] = sb2[n0 + wn + j * 16 + r];
#pragma unroll
    for (int i = 0; i < 4; i++)
#pragma unroll
        for (int g = 0; g < 4; g++) {
            int rowl = wm + i * 16 + q * 4 + g;
            int s0 = sl[rowl * 2], s1 = sl[rowl * 2 + 1];
            float w0 = wl[rowl * 2], w1 = wl[rowl * 2 + 1];
            const u16t* y0p = Yr + (size_t)s0 * DD;
            const u16t* y1p = Yr + (size_t)s1 * DD;
#pragma unroll
            for (int j = 0; j < 4; j++) {
                int col = n0 + wn + j * 16 + r;
                float v = acc[i][j][g] + bv[j];
                v += w0 * bf2f(y0p[col]) + w1 * bf2f(y1p[col]);
                out[(size_t)(m0 + rowl) * DD + col] = v;
            }
        }
}

// ---------------- routed GEMM1 (dual 128x64, gathered, dbuf) ----------------
__global__ __launch_bounds__(256) void k_rgemm1(const u16t* __restrict__ xb,
        const u16t* __restrict__ w1b, const float* __restrict__ b1,
        const u16t* __restrict__ w3b, const float* __restrict__ b3,
        const int* __restrict__ stok,
        const int* __restrict__ texp, const int* __restrict__ tm0,
        u16t* __restrict__ Hr) {
    const int te = texp[blockIdx.x];
    if (te < 0) return;
    const int m0 = tm0[blockIdx.x], n0 = blockIdx.y * 64;
    __shared__ u16t As[2][128 * 32], B1s[2][64 * 32], B3s[2][64 * 32];
    const int tid = threadIdx.x, lane = tid & 63, wid = tid >> 6;
    const int wm = (wid & 1) * 64, wn = (wid >> 1) * 32;
    const int q = lane >> 4, r = lane & 15;
    const int srow = tid >> 2, scg = (tid & 3) * 8;
    // direct broadcast gather of slot->token (4 lanes share one address)
    int t0 = stok[m0 + srow];       if (t0 < 0) t0 = 0;
    int t1 = stok[m0 + 64 + srow];  if (t1 < 0) t1 = 0;
    floatx4 acc1[4][2], acc3[4][2];
#pragma unroll
    for (int i = 0; i < 4; i++)
#pragma unroll
        for (int j = 0; j < 2; j++) { acc1[i][j] = (floatx4)0.f; acc3[i][j] = (floatx4)0.f; }
    const u16t* a0  = xb + (size_t)t0 * DD + scg;
    const u16t* a1  = xb + (size_t)t1 * DD + scg;
    const u16t* b1g = w1b + (size_t)te * DFF * DD + (size_t)(n0 + srow) * DD + scg;
    const u16t* b3g = w3b + (size_t)te * DFF * DD + (size_t)(n0 + srow) * DD + scg;
    const float* b1e = b1 + (size_t)te * DFF;
    const float* b3e = b3 + (size_t)te * DFF;

#define RG1_STAGE(bf, kk) do { \
        glds16(a0 + (kk), &As[bf][tid * 8]); \
        glds16(a1 + (kk), &As[bf][2048 + tid * 8]); \
        glds16(b1g + (kk), &B1s[bf][tid * 8]); \
        glds16(b3g + (kk), &B3s[bf][tid * 8]); \
    } while (0)
#define RG1_COMP(bf) do { \
        bf16x8 af[4], f1[2], f3[2]; \
        _Pragma("unroll") \
        for (int i = 0; i < 4; i++) af[i] = *(const bf16x8*)&As[bf][(wm + i * 16 + r) * 32 + q * 8]; \
        _Pragma("unroll") \
        for (int j = 0; j < 2; j++) { \
            f1[j] = *(const bf16x8*)&B1s[bf][(wn + j * 16 + r) * 32 + q * 8]; \
            f3[j] = *(const bf16x8*)&B3s[bf][(wn + j * 16 + r) * 32 + q * 8]; \
        } \
        _Pragma("unroll") \
        for (int i = 0; i < 4; i++) \
            _Pragma("unroll") \
            for (int j = 0; j < 2; j++) { \
                acc1[i][j] = mfma16(af[i], f1[j], acc1[i][j]); \
                acc3[i][j] = mfma16(af[i], f3[j], acc3[i][j]); \
            } \
    } while (0)

    RG1_STAGE(0, 0);
    __syncthreads();
    for (int k0 = 0; k0 + 64 <= DD; k0 += 64) {
        RG1_STAGE(1, k0 + 32);
        RG1_COMP(0);
        __syncthreads();
        if (k0 + 64 < DD) RG1_STAGE(0, k0 + 64);
        RG1_COMP(1);
        __syncthreads();
    }
#undef RG1_STAGE
#undef RG1_COMP
    float s1v[2], s3v[2];
#pragma unroll
    for (int j = 0; j < 2; j++) {
        int col = n0 + wn + j * 16 + r;
        s1v[j] = b1e[col]; s3v[j] = b3e[col];
    }
#pragma unroll
    for (int i = 0; i < 4; i++)
#pragma unroll
        for (int j = 0; j < 2; j++)
#pragma unroll
            for (int g = 0; g < 4; g++) {
                int slot = m0 + wm + i * 16 + q * 4 + g;
                int col = n0 + wn + j * 16 + r;
                float z1 = acc1[i][j][g] + s1v[j];
                float z3 = acc3[i][j][g] + s3v[j];
                float h = (z1 / (1.f + __expf(-z1))) * z3;
                Hr[(size_t)slot * DFF + col] = f2bf1(h);
            }
}

// ---------------- routed GEMM2 (128x128, dbuf): Yr[slot] = Hr@w2^T + b2 ----------------
__global__ __launch_bounds__(256) void k_rgemm2(const u16t* __restrict__ Hr,
        const u16t* __restrict__ w2b, const float* __restrict__ b2,
        const int* __restrict__ texp, const int* __restrict__ tm0,
        u16t* __restrict__ Yr) {
    const int te = texp[blockIdx.x];
    if (te < 0) return;
    const int m0 = tm0[blockIdx.x], n0 = blockIdx.y * 128;
    __shared__ u16t As[2][128 * 32], Bs[2][128 * 32];
    const int tid = threadIdx.x, lane = tid & 63, wid = tid >> 6;
    const int wm = (wid & 1) * 64, wn = (wid >> 1) * 64;
    const int q = lane >> 4, r = lane & 15;
    const int srow = tid >> 2, scg = (tid & 3) * 8;
    floatx4 acc[4][4];
#pragma unroll
    for (int i = 0; i < 4; i++)
#pragma unroll
        for (int j = 0; j < 4; j++) acc[i][j] = (floatx4)0.f;
    const u16t* a0 = Hr + (size_t)(m0 + srow) * DFF + scg;
    const u16t* a1 = Hr + (size_t)(m0 + 64 + srow) * DFF + scg;
    const u16t* b0 = w2b + (size_t)te * DD * DFF + (size_t)(n0 + srow) * DFF + scg;
    const u16t* b1 = w2b + (size_t)te * DD * DFF + (size_t)(n0 + 64 + srow) * DFF + scg;
    const float* b2e = b2 + (size_t)te * DD;

#define RG2_STAGE(bf, kk) do { \
        glds16(a0 + (kk), &As[bf][tid * 8]); \
        glds16(a1 + (kk), &As[bf][2048 + tid * 8]); \
        glds16(b0 + (kk), &Bs[bf][tid * 8]); \
        glds16(b1 + (kk), &Bs[bf][2048 + tid * 8]); \
    } while (0)
#define RG2_COMP(bf) do { \
        bf16x8 af[4], bfr[4]; \
        _Pragma("unroll") \
        for (int i = 0; i < 4; i++) af[i] = *(const bf16x8*)&As[bf][(wm + i * 16 + r) * 32 + q * 8]; \
        _Pragma("unroll") \
        for (int j = 0; j < 4; j++) bfr[j] = *(const bf16x8*)&Bs[bf][(wn + j * 16 + r) * 32 + q * 8]; \
        _Pragma("unroll") \
        for (int i = 0; i < 4; i++) \
            _Pragma("unroll") \
            for (int j = 0; j < 4; j++) acc[i][j] = mfma16(af[i], bfr[j], acc[i][j]); \
    } while (0)

    RG2_STAGE(0, 0);
    __syncthreads();
    for (int k0 = 0; k0 + 64 <= DFF; k0 += 64) {
        RG2_STAGE(1, k0 + 32);
        RG2_COMP(0);
        __syncthreads();
        if (k0 + 64 < DFF) RG2_STAGE(0, k0 + 64);
        RG2_COMP(1);
        __syncthreads();
    }
#undef RG2_STAGE
#undef RG2_COMP
    float bv[4];
#pragma unroll
    for (int j = 0; j < 4; j++) bv[j] = b2e[n0 + wn + j * 16 + r];
#pragma unroll
    for (int i = 0; i < 4; i++)
#pragma unroll
        for (int g = 0; g < 4; g++) {
            int slot = m0 + wm + i * 16 + q * 4 + g;
#pragma unroll
            for (int j = 0; j < 4; j++) {
                int col = n0 + wn + j * 16 + r;
                Yr[(size_t)slot * DD + col] = f2bf1(acc[i][j][g] + bv[j]);
            }
        }
}

extern "C" void kernel_launch(void* const* d_in, const int* in_sizes, int n_in,
                              void* d_out, int out_size, void* d_ws, size_t ws_size,
                              hipStream_t stream) {
    const float* x   = (const float*)d_in[0];
    const float* gw  = (const float*)d_in[1];
    const float* eb  = (const float*)d_in[2];
    const float* w1  = (const float*)d_in[3];
    const float* b1  = (const float*)d_in[4];
    const float* w3  = (const float*)d_in[5];
    const float* b3  = (const float*)d_in[6];
    const float* w2  = (const float*)d_in[7];
    const float* b2  = (const float*)d_in[8];
    const float* sw1 = (const float*)d_in[9];
    const float* sb1 = (const float*)d_in[10];
    const float* sw3 = (const float*)d_in[11];
    const float* sb3 = (const float*)d_in[12];
    const float* sw2 = (const float*)d_in[13];
    const float* sb2 = (const float*)d_in[14];
    float* out = (float*)d_out;
    char* ws = (char*)d_ws;

    u16t*  xb   = (u16t*)(ws + XB_OFF);
    u16t*  Hs   = (u16t*)(ws + HS_OFF);
    u16t*  Hr   = (u16t*)(ws + HR_OFF);
    u16t*  Yr   = (u16t*)(ws + YR_OFF);
    u16t*  w1b  = (u16t*)(ws + W1B_OFF);
    u16t*  w3b  = (u16t*)(ws + W3B_OFF);
    u16t*  w2b  = (u16t*)(ws + W2B_OFF);
    u16t*  sw1b = (u16t*)(ws + SW1B_OFF);
    u16t*  sw3b = (u16t*)(ws + SW3B_OFF);
    u16t*  sw2b = (u16t*)(ws + SW2B_OFF);
    int*   tki  = (int*)(ws + TKI_OFF);
    float* tkw  = (float*)(ws + TKW_OFF);
    int*   stok = (int*)(ws + STOK_OFF);
    int*   tslot = (int*)(ws + TSL_OFF);
    int*   lrank = (int*)(ws + LRK_OFF);
    int*   bcnt = (int*)(ws + BCN_OFF);
    int*   bb   = (int*)(ws + BB_OFF);
    int*   offs = (int*)(ws + OFS_OFF);
    int*   texp = (int*)(ws + TEX_OFF);
    int*   tm0  = (int*)(ws + TM0_OFF);

    hipMemsetAsync(stok, 0xFF, (size_t)NSLOT_PAD * 4, stream);  // pad slots = -1

    k_cvtw<<<13824, 256, 0, stream>>>(w1, w3, w2, sw1, sw3, sw2, w1b, w3b, w2b, sw1b, sw3b, sw2b);
    k_gate<<<512, 256, 0, stream>>>(x, gw, eb, tki, tkw, xb);
    k_hist<<<HB, 256, 0, stream>>>(tki, lrank, bcnt);
    k_scan<<<1, 64, 0, stream>>>(bcnt, offs, bb, texp, tm0);
    k_scatter<<<HB, 256, 0, stream>>>(tki, bb, lrank, stok, tslot);

    // routed path first: Yr must be complete before k_sgemm2's fused combine
    k_rgemm1<<<dim3(MAXT, DFF / 64), 256, 0, stream>>>(xb, w1b, b1, w3b, b3, stok, texp, tm0, Hr);
    k_rgemm2<<<dim3(MAXT, DD / 128), 256, 0, stream>>>(Hr, w2b, b2, texp, tm0, Yr);

    k_sgemm1<<<dim3(TT / 128, FDFF / 64), 256, 0, stream>>>(xb, sw1b, sb1, sw3b, sb3, Hs);
    k_sgemm2<<<dim3(TT / 128, DD / 128), 256, 0, stream>>>(Hs, sw2b, sb2, Yr, tslot, tkw, out);
}

// Round 3
// 385.874 us; speedup vs baseline: 1.0903x; 1.0903x over previous
//
#include <hip/hip_runtime.h>
#include <cstdint>
#include <cstddef>

#define DEV static __device__ __forceinline__

constexpr int TT   = 8192;   // B*S tokens
constexpr int DD   = 1024;   // d_model
constexpr int DFF  = 512;
constexpr int NE   = 16;
constexpr int FDFF = 1024;   // fused shared dff
constexpr int NSLOT = TT * 2;                 // token-expert pairs
constexpr int NSLOT_PAD = NSLOT + NE * 128;   // padded to 128-row tiles
constexpr int MAXT = NSLOT / 128 + NE;        // 144 max live m-tiles
constexpr int HB   = 64;                      // hist blocks (256 entries each)

// merged GEMM1 grid: routed (MAXT x 8) + shared (64 x 16), flattened 1D
constexpr int RB1 = MAXT * (DFF / 64);            // 1152 routed blocks
constexpr int SB1 = (TT / 128) * (FDFF / 64);     // 1024 shared blocks
constexpr int NB1 = RB1 + SB1;                    // 2176 (divisible by 8)
constexpr int NB_RG2 = MAXT * (DD / 128);         // 1152
constexpr int NB_SG2 = (TT / 128) * (DD / 128);   // 512

// ---- workspace layout (bytes) ----
constexpr size_t XB_OFF   = 0;                                    // x bf16 [T,D]
constexpr size_t HS_OFF   = XB_OFF  + (size_t)TT * DD * 2;        // shared hidden bf16 [T,FDFF]
constexpr size_t HR_OFF   = HS_OFF  + (size_t)TT * FDFF * 2;      // routed hidden bf16 [NSLOT_PAD,DFF]
constexpr size_t YR_OFF   = HR_OFF  + (size_t)NSLOT_PAD * DFF * 2;// routed out bf16 [NSLOT_PAD,DD]
constexpr size_t W1B_OFF  = YR_OFF  + (size_t)NSLOT_PAD * DD * 2;
constexpr size_t W3B_OFF  = W1B_OFF + (size_t)NE * DFF * DD * 2;
constexpr size_t W2B_OFF  = W3B_OFF + (size_t)NE * DFF * DD * 2;
constexpr size_t SW1B_OFF = W2B_OFF + (size_t)NE * DD * DFF * 2;
constexpr size_t SW3B_OFF = SW1B_OFF + (size_t)FDFF * DD * 2;
constexpr size_t SW2B_OFF = SW3B_OFF + (size_t)FDFF * DD * 2;
constexpr size_t TKI_OFF  = SW2B_OFF + (size_t)DD * FDFF * 2;
constexpr size_t TKW_OFF  = TKI_OFF + (size_t)NSLOT * 4;
constexpr size_t STOK_OFF = TKW_OFF + (size_t)NSLOT * 4;
constexpr size_t TSL_OFF  = STOK_OFF + (size_t)NSLOT_PAD * 4;     // token-pair -> slot [NSLOT]
constexpr size_t LRK_OFF  = TSL_OFF + (size_t)NSLOT * 4;          // local rank [NSLOT]
constexpr size_t BCN_OFF  = LRK_OFF + (size_t)NSLOT * 4;          // blockCnt [HB][16]
constexpr size_t BB_OFF   = BCN_OFF + (size_t)HB * NE * 4;        // blockBase [HB][16]
constexpr size_t OFS_OFF  = BB_OFF + (size_t)HB * NE * 4;         // offsets[17]
constexpr size_t TEX_OFF  = OFS_OFF + 128;                        // tile->expert
constexpr size_t TM0_OFF  = TEX_OFF + (size_t)MAXT * 4;           // tile->slot0

typedef __bf16 bf16x8 __attribute__((ext_vector_type(8)));
typedef float  floatx4 __attribute__((ext_vector_type(4)));
typedef unsigned short u16t;

DEV unsigned f2bf2(float lo, float hi) {
    unsigned a = __builtin_bit_cast(unsigned, lo);
    unsigned b = __builtin_bit_cast(unsigned, hi);
    a += 0x7FFFu + ((a >> 16) & 1u);
    b += 0x7FFFu + ((b >> 16) & 1u);
    return (a >> 16) | (b & 0xFFFF0000u);
}
DEV u16t f2bf1(float f) {
    unsigned u = __builtin_bit_cast(unsigned, f);
    u += 0x7FFFu + ((u >> 16) & 1u);
    return (u16t)(u >> 16);
}
DEV float bf2f(u16t v) {
    return __builtin_bit_cast(float, ((unsigned)v) << 16);
}
DEV uint4 pack8(float4 a, float4 b) {
    uint4 r;
    r.x = f2bf2(a.x, a.y); r.y = f2bf2(a.z, a.w);
    r.z = f2bf2(b.x, b.y); r.w = f2bf2(b.z, b.w);
    return r;
}
DEV floatx4 mfma16(bf16x8 a, bf16x8 b, floatx4 c) {
    return __builtin_amdgcn_mfma_f32_16x16x32_bf16(a, b, c, 0, 0, 0);
}
DEV void glds16(const u16t* g, u16t* l) {   // async global->LDS, 16B/lane
    __builtin_amdgcn_global_load_lds(
        (const __attribute__((address_space(1))) unsigned int*)g,
        (__attribute__((address_space(3))) unsigned int*)l, 16, 0, 0);
}
DEV float dot4(float4 a, float4 b) { return a.x*b.x + a.y*b.y + a.z*b.z + a.w*b.w; }

// ---------------- weight fp32 -> bf16 pre-convert ----------------
__global__ __launch_bounds__(256) void k_cvtw(
        const float* __restrict__ w1, const float* __restrict__ w3, const float* __restrict__ w2,
        const float* __restrict__ sw1, const float* __restrict__ sw3, const float* __restrict__ sw2,
        u16t* __restrict__ w1b, u16t* __restrict__ w3b, u16t* __restrict__ w2b,
        u16t* __restrict__ sw1b, u16t* __restrict__ sw3b, u16t* __restrict__ sw2b) {
    int b = blockIdx.x;
    const float* src; u16t* dst; size_t base;
    if      (b < 4096)  { src = w1;  dst = w1b;  base = (size_t)b * 2048; }
    else if (b < 8192)  { src = w3;  dst = w3b;  base = (size_t)(b - 4096) * 2048; }
    else if (b < 12288) { src = w2;  dst = w2b;  base = (size_t)(b - 8192) * 2048; }
    else if (b < 12800) { src = sw1; dst = sw1b; base = (size_t)(b - 12288) * 2048; }
    else if (b < 13312) { src = sw3; dst = sw3b; base = (size_t)(b - 12800) * 2048; }
    else                { src = sw2; dst = sw2b; base = (size_t)(b - 13312) * 2048; }
    size_t i = base + (size_t)threadIdx.x * 8;
    float4 a = *(const float4*)(src + i);
    float4 c = *(const float4*)(src + i + 4);
    *(uint4*)(dst + i) = pack8(a, c);
}

// ---------------- gate: top-2 + fused x->bf16 conversion ----------------
__global__ __launch_bounds__(256) void k_gate(const float* __restrict__ x,
                                              const float* __restrict__ gw,
                                              const float* __restrict__ eb,
                                              int* __restrict__ tki, float* __restrict__ tkw,
                                              u16t* __restrict__ xb) {
    const int tid = threadIdx.x;
    const int wave = tid >> 6, lane = tid & 63;
    const int tok0 = blockIdx.x * 16 + wave * 4;
    float acc[4][16];
#pragma unroll
    for (int t = 0; t < 4; t++)
#pragma unroll
        for (int e = 0; e < 16; e++) acc[t][e] = 0.f;
#pragma unroll
    for (int i = 0; i < 4; i++) {
        const int d = i * 256 + lane * 4;
        float4 xv[4];
#pragma unroll
        for (int t = 0; t < 4; t++) xv[t] = *(const float4*)(x + (size_t)(tok0 + t) * DD + d);
        // fused bf16 conversion of x (replaces k_cvtx: saves a full re-read of x)
#pragma unroll
        for (int t = 0; t < 4; t++) {
            uint2 p;
            p.x = f2bf2(xv[t].x, xv[t].y);
            p.y = f2bf2(xv[t].z, xv[t].w);
            *(uint2*)(xb + (size_t)(tok0 + t) * DD + d) = p;
        }
#pragma unroll
        for (int e = 0; e < 16; e++) {
            float4 wv = *(const float4*)(gw + (size_t)e * DD + d);
#pragma unroll
            for (int t = 0; t < 4; t++) acc[t][e] += dot4(xv[t], wv);
        }
    }
#pragma unroll
    for (int t = 0; t < 4; t++)
#pragma unroll
        for (int e = 0; e < 16; e++) {
            float v = acc[t][e];
            v += __shfl_xor(v, 1);  v += __shfl_xor(v, 2);  v += __shfl_xor(v, 4);
            v += __shfl_xor(v, 8);  v += __shfl_xor(v, 16); v += __shfl_xor(v, 32);
            acc[t][e] = v;
        }
    if (lane == 0) {
        float ebs[16];
#pragma unroll
        for (int e = 0; e < 16; e++) ebs[e] = eb[e];
#pragma unroll
        for (int t = 0; t < 4; t++) {
            float b0 = -1e30f, b1v = -1e30f, l0 = 0.f, l1 = 0.f;
            int i0 = 0, i1 = 0;
#pragma unroll
            for (int e = 0; e < 16; e++) {
                float lv = acc[t][e];
                float bl = lv + ebs[e];
                if (bl > b0)       { b1v = b0; i1 = i0; l1 = l0; b0 = bl; i0 = e; l0 = lv; }
                else if (bl > b1v) { b1v = bl; i1 = e; l1 = lv; }
            }
            float s0 = 1.f / (1.f + expf(-l0));
            float s1 = 1.f / (1.f + expf(-l1));
            float dn = s0 + s1 + 1e-10f;
            int tok = tok0 + t;
            tki[tok * 2] = i0; tki[tok * 2 + 1] = i1;
            tkw[tok * 2] = s0 / dn; tkw[tok * 2 + 1] = s1 / dn;
        }
    }
}

// ---------------- hist: per-block LDS histogram + local ranks ----------------
__global__ __launch_bounds__(256) void k_hist(const int* __restrict__ tki,
                                              int* __restrict__ lrank, int* __restrict__ bcnt) {
    __shared__ int h[NE];
    const int tid = threadIdx.x;
    if (tid < NE) h[tid] = 0;
    __syncthreads();
    int idx = blockIdx.x * 256 + tid;
    int e = tki[idx];
    lrank[idx] = atomicAdd(&h[e], 1);   // LDS atomic -- no global contention
    __syncthreads();
    if (tid < NE) bcnt[blockIdx.x * NE + tid] = h[tid];
}

// ---------------- scan: expert offsets (128-padded), tile map, block bases ----------------
__global__ void k_scan(const int* __restrict__ bcnt, int* __restrict__ offs,
                       int* __restrict__ bb, int* __restrict__ texp, int* __restrict__ tm0) {
    __shared__ int cntS[NE], offS[NE];
    const int tid = threadIdx.x;
    if (tid < NE) {
        int s = 0;
#pragma unroll
        for (int b = 0; b < HB; b++) s += bcnt[b * NE + tid];
        cntS[tid] = s;
    }
    __syncthreads();
    if (tid == 0) {
        int off = 0, t = 0;
        for (int e = 0; e < NE; e++) {
            offS[e] = off; offs[e] = off;
            int nt = (cntS[e] + 127) >> 7;
            for (int i = 0; i < nt; i++) { texp[t] = e; tm0[t] = off + i * 128; t++; }
            off += nt * 128;
        }
        offs[NE] = off;
        for (; t < MAXT; t++) texp[t] = -1;
    }
    __syncthreads();
    if (tid < NE) {
        int run = offS[tid];
        for (int b = 0; b < HB; b++) { bb[b * NE + tid] = run; run += bcnt[b * NE + tid]; }
    }
}

// ---------------- scatter: pure gather/store, zero atomics; also inverse map ----------------
__global__ __launch_bounds__(256) void k_scatter(const int* __restrict__ tki,
                                                 const int* __restrict__ bb,
                                                 const int* __restrict__ lrank,
                                                 int* __restrict__ stok,
                                                 int* __restrict__ tslot) {
    int idx = blockIdx.x * 256 + threadIdx.x;
    int e = tki[idx];
    int slot = bb[blockIdx.x * NE + e] + lrank[idx];
    stok[slot] = idx >> 1;
    tslot[idx] = slot;          // inverse map: token-pair -> slot (for fused combine)
}

// ---------------- merged GEMM1 (routed + shared, dual 128x64, XCD-swizzled 1D grid) ----
// routed  (swz <  RB1): Hr[slot,  0..512)  = swiglu(x[stok] @ w1^T,  x @ w3^T)  (expert te)
// shared  (swz >= RB1): Hs[token, 0..1024) = swiglu(x @ sw1^T, x @ sw3^T)
// Single-buffered K-loop (r1-proven). XCD chunking: blocks with bid%8==c form a
// contiguous run of logical (m-tile, n) pairs, n-fastest -> same-expert B panels
// and each tile's A panel stay in one XCD's L2.
__global__ __launch_bounds__(256) void k_gemm1(const u16t* __restrict__ xb,
        const u16t* __restrict__ w1b, const float* __restrict__ b1,
        const u16t* __restrict__ w3b, const float* __restrict__ b3,
        const u16t* __restrict__ sw1b, const float* __restrict__ sb1,
        const u16t* __restrict__ sw3b, const float* __restrict__ sb3,
        const int* __restrict__ stok,
        const int* __restrict__ texp, const int* __restrict__ tm0,
        u16t* __restrict__ Hr, u16t* __restrict__ Hs) {
    __shared__ u16t As[128 * 32], B1s[64 * 32], B3s[64 * 32];
    const int tid = threadIdx.x, lane = tid & 63, wid = tid >> 6;
    const int wm = (wid & 1) * 64, wn = (wid >> 1) * 32;
    const int q = lane >> 4, r = lane & 15;
    const int srow = tid >> 2, scg = (tid & 3) * 8;

    const int swz = ((int)blockIdx.x & 7) * (NB1 / 8) + ((int)blockIdx.x >> 3);
    const u16t *a0, *a1, *bg1, *bg3;
    const float *bs1, *bs3;
    u16t* hout; int m0, n0, ostr;
    if (swz < RB1) {
        const int mt = swz >> 3, nb = swz & 7;
        const int te = texp[mt];
        if (te < 0) return;                 // padded dead tile (block-uniform)
        m0 = tm0[mt]; n0 = nb * 64;
        int t0 = stok[m0 + srow];      if (t0 < 0) t0 = 0;
        int t1 = stok[m0 + 64 + srow]; if (t1 < 0) t1 = 0;
        a0 = xb + (size_t)t0 * DD + scg;
        a1 = xb + (size_t)t1 * DD + scg;
        bg1 = w1b + (size_t)te * DFF * DD + (size_t)(n0 + srow) * DD + scg;
        bg3 = w3b + (size_t)te * DFF * DD + (size_t)(n0 + srow) * DD + scg;
        bs1 = b1 + (size_t)te * DFF;
        bs3 = b3 + (size_t)te * DFF;
        hout = Hr; ostr = DFF;
    } else {
        const int s = swz - RB1;
        const int mt = s >> 4, nb = s & 15;
        m0 = mt * 128; n0 = nb * 64;
        a0 = xb + (size_t)(m0 + srow) * DD + scg;
        a1 = xb + (size_t)(m0 + 64 + srow) * DD + scg;
        bg1 = sw1b + (size_t)(n0 + srow) * DD + scg;
        bg3 = sw3b + (size_t)(n0 + srow) * DD + scg;
        bs1 = sb1; bs3 = sb3;
        hout = Hs; ostr = FDFF;
    }

    floatx4 acc1[4][2], acc3[4][2];
#pragma unroll
    for (int i = 0; i < 4; i++)
#pragma unroll
        for (int j = 0; j < 2; j++) { acc1[i][j] = (floatx4)0.f; acc3[i][j] = (floatx4)0.f; }
    u16t* lA0 = As + tid * 8;
    u16t* lA1 = As + 2048 + tid * 8;
    u16t* lB1 = B1s + tid * 8;
    u16t* lB3 = B3s + tid * 8;
    for (int k0 = 0; k0 < DD; k0 += 32) {
        glds16(a0 + k0, lA0); glds16(a1 + k0, lA1);
        glds16(bg1 + k0, lB1); glds16(bg3 + k0, lB3);
        __syncthreads();
        bf16x8 af[4], f1[2], f3[2];
#pragma unroll
        for (int i = 0; i < 4; i++) af[i] = *(const bf16x8*)&As[(wm + i * 16 + r) * 32 + q * 8];
#pragma unroll
        for (int j = 0; j < 2; j++) {
            f1[j] = *(const bf16x8*)&B1s[(wn + j * 16 + r) * 32 + q * 8];
            f3[j] = *(const bf16x8*)&B3s[(wn + j * 16 + r) * 32 + q * 8];
        }
#pragma unroll
        for (int i = 0; i < 4; i++)
#pragma unroll
            for (int j = 0; j < 2; j++) {
                acc1[i][j] = mfma16(af[i], f1[j], acc1[i][j]);
                acc3[i][j] = mfma16(af[i], f3[j], acc3[i][j]);
            }
        __syncthreads();
    }
    float s1v[2], s3v[2];
#pragma unroll
    for (int j = 0; j < 2; j++) {
        int col = n0 + wn + j * 16 + r;
        s1v[j] = bs1[col]; s3v[j] = bs3[col];
    }
#pragma unroll
    for (int i = 0; i < 4; i++)
#pragma unroll
        for (int j = 0; j < 2; j++)
#pragma unroll
            for (int g = 0; g < 4; g++) {
                int row = m0 + wm + i * 16 + q * 4 + g;
                int col = n0 + wn + j * 16 + r;
                float z1 = acc1[i][j][g] + s1v[j];
                float z3 = acc3[i][j][g] + s3v[j];
                float h = (z1 / (1.f + __expf(-z1))) * z3;
                hout[(size_t)row * ostr + col] = f2bf1(h);
            }
}

// ---------------- routed GEMM2 (128x128, swizzled): Yr[slot] = Hr@w2^T + b2 ----------------
__global__ __launch_bounds__(256) void k_rgemm2(const u16t* __restrict__ Hr,
        const u16t* __restrict__ w2b, const float* __restrict__ b2,
        const int* __restrict__ texp, const int* __restrict__ tm0,
        u16t* __restrict__ Yr) {
    const int swz = ((int)blockIdx.x & 7) * (NB_RG2 / 8) + ((int)blockIdx.x >> 3);
    const int mt = swz >> 3, nb = swz & 7;
    const int te = texp[mt];
    if (te < 0) return;
    const int m0 = tm0[mt], n0 = nb * 128;
    __shared__ u16t As[128 * 32], Bs[128 * 32];
    const int tid = threadIdx.x, lane = tid & 63, wid = tid >> 6;
    const int wm = (wid & 1) * 64, wn = (wid >> 1) * 64;
    const int q = lane >> 4, r = lane & 15;
    const int srow = tid >> 2, scg = (tid & 3) * 8;
    floatx4 acc[4][4];
#pragma unroll
    for (int i = 0; i < 4; i++)
#pragma unroll
        for (int j = 0; j < 4; j++) acc[i][j] = (floatx4)0.f;
    const u16t* a0 = Hr + (size_t)(m0 + srow) * DFF + scg;
    const u16t* a1 = Hr + (size_t)(m0 + 64 + srow) * DFF + scg;
    const u16t* b0 = w2b + (size_t)te * DD * DFF + (size_t)(n0 + srow) * DFF + scg;
    const u16t* b1 = w2b + (size_t)te * DD * DFF + (size_t)(n0 + 64 + srow) * DFF + scg;
    const float* b2e = b2 + (size_t)te * DD;
    u16t* lA0 = As + tid * 8;       u16t* lA1 = As + 2048 + tid * 8;
    u16t* lB0 = Bs + tid * 8;       u16t* lB1 = Bs + 2048 + tid * 8;
    for (int k0 = 0; k0 < DFF; k0 += 32) {
        glds16(a0 + k0, lA0); glds16(a1 + k0, lA1);
        glds16(b0 + k0, lB0); glds16(b1 + k0, lB1);
        __syncthreads();
        bf16x8 af[4], bf[4];
#pragma unroll
        for (int i = 0; i < 4; i++) af[i] = *(const bf16x8*)&As[(wm + i * 16 + r) * 32 + q * 8];
#pragma unroll
        for (int j = 0; j < 4; j++) bf[j] = *(const bf16x8*)&Bs[(wn + j * 16 + r) * 32 + q * 8];
#pragma unroll
        for (int i = 0; i < 4; i++)
#pragma unroll
            for (int j = 0; j < 4; j++) acc[i][j] = mfma16(af[i], bf[j], acc[i][j]);
        __syncthreads();
    }
    float bv[4];
#pragma unroll
    for (int j = 0; j < 4; j++) bv[j] = b2e[n0 + wn + j * 16 + r];
#pragma unroll
    for (int i = 0; i < 4; i++)
#pragma unroll
        for (int g = 0; g < 4; g++) {
            int slot = m0 + wm + i * 16 + q * 4 + g;
#pragma unroll
            for (int j = 0; j < 4; j++) {
                int col = n0 + wn + j * 16 + r;
                Yr[(size_t)slot * DD + col] = f2bf1(acc[i][j][g] + bv[j]);
            }
        }
}

// ---------------- shared GEMM2 + fused routed combine (swizzled) ----------------
// out[t] = Hs[t]@sw2^T + sb2 + tkw[t,0]*Yr[slot0] + tkw[t,1]*Yr[slot1]
__global__ __launch_bounds__(256) void k_sgemm2(const u16t* __restrict__ Hs,
        const u16t* __restrict__ sw2b, const float* __restrict__ sb2,
        const u16t* __restrict__ Yr, const int* __restrict__ tslot,
        const float* __restrict__ tkw,
        float* __restrict__ out) {
    const int swz = ((int)blockIdx.x & 7) * (NB_SG2 / 8) + ((int)blockIdx.x >> 3);
    const int mt = swz >> 3, nb = swz & 7;
    const int m0 = mt * 128, n0 = nb * 128;
    __shared__ u16t As[128 * 32], Bs[128 * 32];
    __shared__ int sl[256];
    __shared__ float wl[256];
    const int tid = threadIdx.x, lane = tid & 63, wid = tid >> 6;
    const int wm = (wid & 1) * 64, wn = (wid >> 1) * 64;
    const int q = lane >> 4, r = lane & 15;
    const int srow = tid >> 2, scg = (tid & 3) * 8;
    sl[tid] = tslot[m0 * 2 + tid];
    wl[tid] = tkw[m0 * 2 + tid];
    floatx4 acc[4][4];
#pragma unroll
    for (int i = 0; i < 4; i++)
#pragma unroll
        for (int j = 0; j < 4; j++) acc[i][j] = (floatx4)0.f;
    const u16t* a0 = Hs + (size_t)(m0 + srow) * FDFF + scg;
    const u16t* a1 = Hs + (size_t)(m0 + 64 + srow) * FDFF + scg;
    const u16t* b0 = sw2b + (size_t)(n0 + srow) * FDFF + scg;
    const u16t* b1 = sw2b + (size_t)(n0 + 64 + srow) * FDFF + scg;
    u16t* lA0 = As + tid * 8;       u16t* lA1 = As + 2048 + tid * 8;
    u16t* lB0 = Bs + tid * 8;       u16t* lB1 = Bs + 2048 + tid * 8;
    for (int k0 = 0; k0 < FDFF; k0 += 32) {
        glds16(a0 + k0, lA0); glds16(a1 + k0, lA1);
        glds16(b0 + k0, lB0); glds16(b1 + k0, lB1);
        __syncthreads();
        bf16x8 af[4], bf[4];
#pragma unroll
        for (int i = 0; i < 4; i++) af[i] = *(const bf16x8*)&As[(wm + i * 16 + r) * 32 + q * 8];
#pragma unroll
        for (int j = 0; j < 4; j++) bf[j] = *(const bf16x8*)&Bs[(wn + j * 16 + r) * 32 + q * 8];
#pragma unroll
        for (int i = 0; i < 4; i++)
#pragma unroll
            for (int j = 0; j < 4; j++) acc[i][j] = mfma16(af[i], bf[j], acc[i][j]);
        __syncthreads();
    }
    float bv[4];
#pragma unroll
    for (int j = 0; j < 4; j++) bv[j] = sb2[n0 + wn + j * 16 + r];
#pragma unroll
    for (int i = 0; i < 4; i++)
#pragma unroll
        for (int g = 0; g < 4; g++) {
            int rowl = wm + i * 16 + q * 4 + g;
            int s0 = sl[rowl * 2], s1 = sl[rowl * 2 + 1];
            float w0 = wl[rowl * 2], w1 = wl[rowl * 2 + 1];
            const u16t* y0p = Yr + (size_t)s0 * DD;
            const u16t* y1p = Yr + (size_t)s1 * DD;
#pragma unroll
            for (int j = 0; j < 4; j++) {
                int col = n0 + wn + j * 16 + r;
                float v = acc[i][j][g] + bv[j];
                v += w0 * bf2f(y0p[col]) + w1 * bf2f(y1p[col]);
                out[(size_t)(m0 + rowl) * DD + col] = v;
            }
        }
}

extern "C" void kernel_launch(void* const* d_in, const int* in_sizes, int n_in,
                              void* d_out, int out_size, void* d_ws, size_t ws_size,
                              hipStream_t stream) {
    const float* x   = (const float*)d_in[0];
    const float* gw  = (const float*)d_in[1];
    const float* eb  = (const float*)d_in[2];
    const float* w1  = (const float*)d_in[3];
    const float* b1  = (const float*)d_in[4];
    const float* w3  = (const float*)d_in[5];
    const float* b3  = (const float*)d_in[6];
    const float* w2  = (const float*)d_in[7];
    const float* b2  = (const float*)d_in[8];
    const float* sw1 = (const float*)d_in[9];
    const float* sb1 = (const float*)d_in[10];
    const float* sw3 = (const float*)d_in[11];
    const float* sb3 = (const float*)d_in[12];
    const float* sw2 = (const float*)d_in[13];
    const float* sb2 = (const float*)d_in[14];
    float* out = (float*)d_out;
    char* ws = (char*)d_ws;

    u16t*  xb   = (u16t*)(ws + XB_OFF);
    u16t*  Hs   = (u16t*)(ws + HS_OFF);
    u16t*  Hr   = (u16t*)(ws + HR_OFF);
    u16t*  Yr   = (u16t*)(ws + YR_OFF);
    u16t*  w1b  = (u16t*)(ws + W1B_OFF);
    u16t*  w3b  = (u16t*)(ws + W3B_OFF);
    u16t*  w2b  = (u16t*)(ws + W2B_OFF);
    u16t*  sw1b = (u16t*)(ws + SW1B_OFF);
    u16t*  sw3b = (u16t*)(ws + SW3B_OFF);
    u16t*  sw2b = (u16t*)(ws + SW2B_OFF);
    int*   tki  = (int*)(ws + TKI_OFF);
    float* tkw  = (float*)(ws + TKW_OFF);
    int*   stok = (int*)(ws + STOK_OFF);
    int*   tslot = (int*)(ws + TSL_OFF);
    int*   lrank = (int*)(ws + LRK_OFF);
    int*   bcnt = (int*)(ws + BCN_OFF);
    int*   bb   = (int*)(ws + BB_OFF);
    int*   offs = (int*)(ws + OFS_OFF);
    int*   texp = (int*)(ws + TEX_OFF);
    int*   tm0  = (int*)(ws + TM0_OFF);

    hipMemsetAsync(stok, 0xFF, (size_t)NSLOT_PAD * 4, stream);  // pad slots = -1

    k_cvtw<<<13824, 256, 0, stream>>>(w1, w3, w2, sw1, sw3, sw2, w1b, w3b, w2b, sw1b, sw3b, sw2b);
    k_gate<<<512, 256, 0, stream>>>(x, gw, eb, tki, tkw, xb);
    k_hist<<<HB, 256, 0, stream>>>(tki, lrank, bcnt);
    k_scan<<<1, 64, 0, stream>>>(bcnt, offs, bb, texp, tm0);
    k_scatter<<<HB, 256, 0, stream>>>(tki, bb, lrank, stok, tslot);

    // merged GEMM1 (routed + shared), then routed GEMM2, then shared GEMM2+combine
    k_gemm1<<<NB1, 256, 0, stream>>>(xb, w1b, b1, w3b, b3, sw1b, sb1, sw3b, sb3,
                                     stok, texp, tm0, Hr, Hs);
    k_rgemm2<<<NB_RG2, 256, 0, stream>>>(Hr, w2b, b2, texp, tm0, Yr);
    k_sgemm2<<<NB_SG2, 256, 0, stream>>>(Hs, sw2b, sb2, Yr, tslot, tkw, out);
}